// Round 1
// baseline (4248.097 us; speedup 1.0000x reference)
//
#include <hip/hip_runtime.h>
#include <math.h>

// ---------------------------------------------------------------------------
// TransformerBlock (ViT-style global + local attention + MLP), fp32 baseline.
// B=2, N=3137 (1 cls + 16*196 patches), C=512, 8 heads, hd=64, H=2048.
// ---------------------------------------------------------------------------

static __device__ __forceinline__ float4 ld4(const float* p) {
    return *reinterpret_cast<const float4*>(p);
}
static __device__ __forceinline__ void st4(float* p, float4 v) {
    *reinterpret_cast<float4*>(p) = v;
}
static __device__ __forceinline__ float4 f4_fma(float4 a, float4 b, float4 c) {
    return make_float4(fmaf(a.x, b.x, c.x), fmaf(a.y, b.y, c.y),
                       fmaf(a.z, b.z, c.z), fmaf(a.w, b.w, c.w));
}
static __device__ __forceinline__ float4 f4_fmas(float s, float4 b, float4 c) {
    return make_float4(fmaf(s, b.x, c.x), fmaf(s, b.y, c.y),
                       fmaf(s, b.z, c.z), fmaf(s, b.w, c.w));
}
static __device__ __forceinline__ float4 f4_scale(float4 a, float s) {
    return make_float4(a.x * s, a.y * s, a.z * s, a.w * s);
}

// ---------------------------------------------------------------------------
// LayerNorm: one wave per row of 512. mode=1: input rows are the patch rows of
// a (2,3137,512) tensor (skip cls): in_row = r + 1 + r/3136.
// ---------------------------------------------------------------------------
__global__ __launch_bounds__(64) void ln_kernel(
    const float* __restrict__ in, const float* __restrict__ g,
    const float* __restrict__ bta, float* __restrict__ out, int mode)
{
    int r = blockIdx.x;
    int lane = threadIdx.x;
    int in_r = mode ? (r + 1 + r / 3136) : r;
    const float* xp = in + (size_t)in_r * 512 + lane * 8;
    float4 v0 = ld4(xp), v1 = ld4(xp + 4);
    float s  = v0.x + v0.y + v0.z + v0.w + v1.x + v1.y + v1.z + v1.w;
    float sq = v0.x*v0.x + v0.y*v0.y + v0.z*v0.z + v0.w*v0.w
             + v1.x*v1.x + v1.y*v1.y + v1.z*v1.z + v1.w*v1.w;
    #pragma unroll
    for (int off = 32; off; off >>= 1) {
        s  += __shfl_xor(s, off);
        sq += __shfl_xor(sq, off);
    }
    float mean = s * (1.f / 512.f);
    float var  = fmaxf(sq * (1.f / 512.f) - mean * mean, 0.f);
    float rstd = rsqrtf(var + 1e-5f);
    float4 g0 = ld4(g + lane * 8),   g1 = ld4(g + lane * 8 + 4);
    float4 b0 = ld4(bta + lane * 8), b1 = ld4(bta + lane * 8 + 4);
    float4 r0, r1;
    r0.x = (v0.x - mean) * rstd * g0.x + b0.x;
    r0.y = (v0.y - mean) * rstd * g0.y + b0.y;
    r0.z = (v0.z - mean) * rstd * g0.z + b0.z;
    r0.w = (v0.w - mean) * rstd * g0.w + b0.w;
    r1.x = (v1.x - mean) * rstd * g1.x + b1.x;
    r1.y = (v1.y - mean) * rstd * g1.y + b1.y;
    r1.z = (v1.z - mean) * rstd * g1.z + b1.z;
    r1.w = (v1.w - mean) * rstd * g1.w + b1.w;
    float* op = out + (size_t)r * 512 + lane * 8;
    st4(op, r0);
    st4(op + 4, r1);
}

// ---------------------------------------------------------------------------
// Generic GEMM: out[maprow(m)] (+)= A[m,:] @ W[:,n] + bias[n]  (+gelu)(+resid)
// A: MxK contiguous, W: KxN row-major. BM=BN=128, BK=16, 256 threads, 8x8/thr.
// rowmap=1: out/resid row = m + 1 + m/3136 (patch rows of (2,3137,C) tensor).
// ---------------------------------------------------------------------------
__global__ __launch_bounds__(256) void gemm_kernel(
    const float* __restrict__ A, const float* __restrict__ W,
    const float* __restrict__ bias, const float* __restrict__ resid,
    float* __restrict__ out, int M, int N, int K, int rowmap, int act)
{
    __shared__ float As[16][132];
    __shared__ float Bs[16][132];

    int tid = threadIdx.x;
    int tx = tid & 15, ty = tid >> 4;
    int m0 = blockIdx.x * 128, n0 = blockIdx.y * 128;

    float acc[8][8];
    #pragma unroll
    for (int i = 0; i < 8; ++i)
        #pragma unroll
        for (int j = 0; j < 8; ++j) acc[i][j] = 0.f;

    int a_m  = tid >> 2;          // 0..63
    int a_k4 = (tid & 3) * 4;     // 0,4,8,12
    int b_k  = tid >> 5;          // 0..7
    int b_n  = (tid & 31) * 4;    // 0..124

    for (int k0 = 0; k0 < K; k0 += 16) {
        #pragma unroll
        for (int p = 0; p < 2; ++p) {
            int m = a_m + 64 * p;
            int row = m0 + m;
            float4 v = (row < M) ? ld4(A + (size_t)row * K + k0 + a_k4)
                                 : make_float4(0.f, 0.f, 0.f, 0.f);
            As[a_k4 + 0][m] = v.x;
            As[a_k4 + 1][m] = v.y;
            As[a_k4 + 2][m] = v.z;
            As[a_k4 + 3][m] = v.w;
        }
        #pragma unroll
        for (int p = 0; p < 2; ++p) {
            int k = b_k + 8 * p;
            float4 v = ld4(W + (size_t)(k0 + k) * N + n0 + b_n);
            st4(&Bs[k][b_n], v);
        }
        __syncthreads();

        #pragma unroll
        for (int kk = 0; kk < 16; ++kk) {
            float4 a0 = ld4(&As[kk][ty * 4]);
            float4 a1 = ld4(&As[kk][64 + ty * 4]);
            float4 b0 = ld4(&Bs[kk][tx * 4]);
            float4 b1 = ld4(&Bs[kk][64 + tx * 4]);
            float av[8] = {a0.x, a0.y, a0.z, a0.w, a1.x, a1.y, a1.z, a1.w};
            float bv[8] = {b0.x, b0.y, b0.z, b0.w, b1.x, b1.y, b1.z, b1.w};
            #pragma unroll
            for (int i = 0; i < 8; ++i)
                #pragma unroll
                for (int j = 0; j < 8; ++j)
                    acc[i][j] = fmaf(av[i], bv[j], acc[i][j]);
        }
        __syncthreads();
    }

    #pragma unroll
    for (int i = 0; i < 8; ++i) {
        int row = m0 + (i >> 2) * 64 + ty * 4 + (i & 3);
        if (row >= M) continue;
        int orow = rowmap ? (row + 1 + row / 3136) : row;
        const float* rp = resid ? resid + (size_t)orow * N : nullptr;
        float* op = out + (size_t)orow * N;
        #pragma unroll
        for (int j = 0; j < 8; ++j) {
            int col = n0 + (j >> 2) * 64 + tx * 4 + (j & 3);
            float v = acc[i][j] + bias[col];
            if (act == 1) v = 0.5f * v * (1.f + erff(v * 0.70710678118654752f));
            if (rp) v += rp[col];
            op[col] = v;
        }
    }
}

// ---------------------------------------------------------------------------
// Flash attention (fp32, online softmax). One thread owns one query row.
// qkv rows: [q(512) | k(512) | v(512)], row index = b*Ns + n.
// Output written in (b, n, h*64+d) layout (C=512 contiguous rows).
// grid: (ceil(Ns/256), 8 heads, NB batches), block 256.
// ---------------------------------------------------------------------------
__global__ __launch_bounds__(256) void attn_kernel(
    const float* __restrict__ qkv, float* __restrict__ o, int Ns)
{
    __shared__ float Ks[32][68];
    __shared__ float Vs[32][68];

    int tid = threadIdx.x;
    int h = blockIdx.y;
    int b = blockIdx.z;
    size_t base = (size_t)b * Ns * 1536;

    int qrow = blockIdx.x * 256 + tid;
    bool valid = qrow < Ns;
    int qr = valid ? qrow : (Ns - 1);

    const float* qp = qkv + base + (size_t)qr * 1536 + h * 64;
    float4 q[16];
    #pragma unroll
    for (int i = 0; i < 16; ++i) q[i] = f4_scale(ld4(qp + i * 4), 0.125f);

    float4 oacc[16];
    #pragma unroll
    for (int i = 0; i < 16; ++i) oacc[i] = make_float4(0.f, 0.f, 0.f, 0.f);
    float m = -1e30f, l = 0.f;

    int srow = tid >> 4;          // 0..15
    int scol = (tid & 15) * 4;    // 0..60
    int nt = (Ns + 31) / 32;

    for (int kt = 0; kt < nt; ++kt) {
        #pragma unroll
        for (int p = 0; p < 2; ++p) {
            int j = srow + 16 * p;
            int krow = kt * 32 + j;
            int kr = (krow < Ns) ? krow : (Ns - 1);
            const float* kp = qkv + base + (size_t)kr * 1536 + 512 + h * 64 + scol;
            st4(&Ks[j][scol], ld4(kp));
            st4(&Vs[j][scol], ld4(kp + 512));
        }
        __syncthreads();

        float s[32];
        #pragma unroll
        for (int j = 0; j < 32; ++j) {
            const float4* kr4 = reinterpret_cast<const float4*>(&Ks[j][0]);
            float4 a4 = make_float4(0.f, 0.f, 0.f, 0.f);
            #pragma unroll
            for (int d = 0; d < 16; ++d) a4 = f4_fma(q[d], kr4[d], a4);
            float sv = a4.x + a4.y + a4.z + a4.w;
            s[j] = (kt * 32 + j < Ns) ? sv : -1e30f;
        }

        float tm = s[0];
        #pragma unroll
        for (int j = 1; j < 32; ++j) tm = fmaxf(tm, s[j]);
        float mnew = fmaxf(m, tm);
        float sc_old = __expf(m - mnew);
        l *= sc_old;
        #pragma unroll
        for (int i = 0; i < 16; ++i) oacc[i] = f4_scale(oacc[i], sc_old);

        #pragma unroll
        for (int j = 0; j < 32; ++j) {
            float p = __expf(s[j] - mnew);
            l += p;
            const float4* vr4 = reinterpret_cast<const float4*>(&Vs[j][0]);
            #pragma unroll
            for (int d = 0; d < 16; ++d) oacc[d] = f4_fmas(p, vr4[d], oacc[d]);
        }
        m = mnew;
        __syncthreads();
    }

    if (valid) {
        float inv = 1.f / l;
        float* op = o + ((size_t)b * Ns + qr) * 512 + h * 64;
        #pragma unroll
        for (int i = 0; i < 16; ++i) st4(op + i * 4, f4_scale(oacc[i], inv));
    }
}

// ---------------------------------------------------------------------------
extern "C" void kernel_launch(void* const* d_in, const int* in_sizes, int n_in,
                              void* d_out, int out_size, void* d_ws, size_t ws_size,
                              hipStream_t stream)
{
    const float* x       = (const float*)d_in[0];
    const float* ln1_g   = (const float*)d_in[2];
    const float* ln1_b   = (const float*)d_in[3];
    const float* ln2_g   = (const float*)d_in[4];
    const float* ln2_b   = (const float*)d_in[5];
    const float* ln3_g   = (const float*)d_in[6];
    const float* ln3_b   = (const float*)d_in[7];
    const float* g_qkv_w = (const float*)d_in[8];
    const float* g_qkv_b = (const float*)d_in[9];
    const float* g_proj_w= (const float*)d_in[10];
    const float* g_proj_b= (const float*)d_in[11];
    const float* l_qkv_w = (const float*)d_in[12];
    const float* l_qkv_b = (const float*)d_in[13];
    const float* l_proj_w= (const float*)d_in[14];
    const float* l_proj_b= (const float*)d_in[15];
    const float* mlp_w1  = (const float*)d_in[16];
    const float* mlp_b1  = (const float*)d_in[17];
    const float* mlp_w2  = (const float*)d_in[18];
    const float* mlp_b2  = (const float*)d_in[19];

    float* out = (float*)d_out;           // also serves as x1/x2 running buffer

    // Workspace: buf_a = 6274*512 (ln out / attn out), buf_b = 6274*2048 (qkv / mlp hidden)
    float* buf_a = (float*)d_ws;
    float* buf_b = buf_a + (size_t)6274 * 512;

    // 1) ln1 = LN(x)
    ln_kernel<<<dim3(6274), dim3(64), 0, stream>>>(x, ln1_g, ln1_b, buf_a, 0);
    // 2) qkv_g = ln1 @ g_qkv_w + b   (6274 x 1536)
    gemm_kernel<<<dim3(50, 12), dim3(256), 0, stream>>>(
        buf_a, g_qkv_w, g_qkv_b, nullptr, buf_b, 6274, 1536, 512, 0, 0);
    // 3) global attention (B=2, Ns=3137) -> buf_a (B,N,C)
    attn_kernel<<<dim3(13, 8, 2), dim3(256), 0, stream>>>(buf_b, buf_a, 3137);
    // 4) x1 = x + attn_o @ g_proj_w + b   -> out
    gemm_kernel<<<dim3(50, 4), dim3(256), 0, stream>>>(
        buf_a, g_proj_w, g_proj_b, x, out, 6274, 512, 512, 0, 0);
    // 5) ln2 = LN(patches of x1)  (6272 contiguous rows)
    ln_kernel<<<dim3(6272), dim3(64), 0, stream>>>(out, ln2_g, ln2_b, buf_a, 1);
    // 6) qkv_l = ln2 @ l_qkv_w + b   (6272 x 1536)
    gemm_kernel<<<dim3(49, 12), dim3(256), 0, stream>>>(
        buf_a, l_qkv_w, l_qkv_b, nullptr, buf_b, 6272, 1536, 512, 0, 0);
    // 7) local attention (32 sub-batches, Ns=196) -> buf_a (rows b'*196+n)
    attn_kernel<<<dim3(1, 8, 32), dim3(256), 0, stream>>>(buf_b, buf_a, 196);
    // 8) patches += local @ l_proj_w + b   (in-place on out, patch-row mapped)
    gemm_kernel<<<dim3(49, 4), dim3(256), 0, stream>>>(
        buf_a, l_proj_w, l_proj_b, out, out, 6272, 512, 512, 1, 0);
    // 9) ln3 = LN(x2)
    ln_kernel<<<dim3(6274), dim3(64), 0, stream>>>(out, ln3_g, ln3_b, buf_a, 0);
    // 10) h = gelu(ln3 @ w1 + b1)   (6274 x 2048)
    gemm_kernel<<<dim3(50, 16), dim3(256), 0, stream>>>(
        buf_a, mlp_w1, mlp_b1, nullptr, buf_b, 6274, 2048, 512, 0, 1);
    // 11) out = x2 + h @ w2 + b2   (in-place residual on out)
    gemm_kernel<<<dim3(50, 4), dim3(256), 0, stream>>>(
        buf_b, mlp_w2, mlp_b2, out, out, 6274, 512, 2048, 0, 0);
}

// Round 2
// 2159.841 us; speedup vs baseline: 1.9669x; 1.9669x over previous
//
#include <hip/hip_runtime.h>
#include <math.h>

typedef __attribute__((ext_vector_type(8))) short bf16x8;
typedef __attribute__((ext_vector_type(4))) float f32x4;
typedef __attribute__((ext_vector_type(4))) unsigned int u32x4;

static __device__ __forceinline__ float4 ld4(const float* p) {
    return *reinterpret_cast<const float4*>(p);
}
static __device__ __forceinline__ void st4(float* p, float4 v) {
    *reinterpret_cast<float4*>(p) = v;
}
static __device__ __forceinline__ float4 f4_fma(float4 a, float4 b, float4 c) {
    return make_float4(fmaf(a.x, b.x, c.x), fmaf(a.y, b.y, c.y),
                       fmaf(a.z, b.z, c.z), fmaf(a.w, b.w, c.w));
}
static __device__ __forceinline__ float4 f4_fmas(float s, float4 b, float4 c) {
    return make_float4(fmaf(s, b.x, c.x), fmaf(s, b.y, c.y),
                       fmaf(s, b.z, c.z), fmaf(s, b.w, c.w));
}
static __device__ __forceinline__ float4 f4_scale(float4 a, float s) {
    return make_float4(a.x * s, a.y * s, a.z * s, a.w * s);
}
static __device__ __forceinline__ unsigned short f2bf(float f) {
    unsigned int u = __float_as_uint(f);
    u += 0x7fffu + ((u >> 16) & 1u);
    return (unsigned short)(u >> 16);
}

// ---------------------------------------------------------------------------
// LayerNorm: one wave per row of 512. mode=1: in_row = r + 1 + r/3136.
// ---------------------------------------------------------------------------
__global__ __launch_bounds__(64) void ln_kernel(
    const float* __restrict__ in, const float* __restrict__ g,
    const float* __restrict__ bta, float* __restrict__ out, int mode)
{
    int r = blockIdx.x;
    int lane = threadIdx.x;
    int in_r = mode ? (r + 1 + r / 3136) : r;
    const float* xp = in + (size_t)in_r * 512 + lane * 8;
    float4 v0 = ld4(xp), v1 = ld4(xp + 4);
    float s  = v0.x + v0.y + v0.z + v0.w + v1.x + v1.y + v1.z + v1.w;
    float sq = v0.x*v0.x + v0.y*v0.y + v0.z*v0.z + v0.w*v0.w
             + v1.x*v1.x + v1.y*v1.y + v1.z*v1.z + v1.w*v1.w;
    #pragma unroll
    for (int off = 32; off; off >>= 1) {
        s  += __shfl_xor(s, off);
        sq += __shfl_xor(sq, off);
    }
    float mean = s * (1.f / 512.f);
    float var  = fmaxf(sq * (1.f / 512.f) - mean * mean, 0.f);
    float rstd = rsqrtf(var + 1e-5f);
    float4 g0 = ld4(g + lane * 8),   g1 = ld4(g + lane * 8 + 4);
    float4 b0 = ld4(bta + lane * 8), b1 = ld4(bta + lane * 8 + 4);
    float4 r0, r1;
    r0.x = (v0.x - mean) * rstd * g0.x + b0.x;
    r0.y = (v0.y - mean) * rstd * g0.y + b0.y;
    r0.z = (v0.z - mean) * rstd * g0.z + b0.z;
    r0.w = (v0.w - mean) * rstd * g0.w + b0.w;
    r1.x = (v1.x - mean) * rstd * g1.x + b1.x;
    r1.y = (v1.y - mean) * rstd * g1.y + b1.y;
    r1.z = (v1.z - mean) * rstd * g1.z + b1.z;
    r1.w = (v1.w - mean) * rstd * g1.w + b1.w;
    float* op = out + (size_t)r * 512 + lane * 8;
    st4(op, r0);
    st4(op + 4, r1);
}

// ---------------------------------------------------------------------------
// Weight transpose + fp32->bf16: W[K][N] -> WT[N][K] bf16.
// grid (N/32, K/32), block (32,8).
// ---------------------------------------------------------------------------
__global__ __launch_bounds__(256) void transpose_bf16_kernel(
    const float* __restrict__ W, unsigned short* __restrict__ WT, int K, int N)
{
    __shared__ unsigned short tile[32][34];
    int tx = threadIdx.x, ty = threadIdx.y;
    int bx = blockIdx.x * 32, by = blockIdx.y * 32;
    #pragma unroll
    for (int r = 0; r < 32; r += 8)
        tile[ty + r][tx] = f2bf(W[(size_t)(by + ty + r) * N + bx + tx]);
    __syncthreads();
    #pragma unroll
    for (int r = 0; r < 32; r += 8)
        WT[(size_t)(bx + ty + r) * K + by + tx] = tile[tx][ty + r];
}

// ---------------------------------------------------------------------------
// MFMA bf16 GEMM: out[maprow(m)] (+)= A[m,:] @ WT[n,:] + bias[n] (+gelu)(+resid)
// A: MxK (fp32 or bf16), WT: NxK bf16 (pre-transposed). BM=BN=128, BK=32.
// 256 threads = 4 waves (2x2), each wave 64x64 via 4x4 frags of 16x16x32 MFMA.
// ---------------------------------------------------------------------------
template<int A_BF16, int OUT_BF16>
__global__ __launch_bounds__(256) void mfma_gemm(
    const void* __restrict__ Ap, const unsigned short* __restrict__ WT,
    const float* __restrict__ bias, const float* __restrict__ resid,
    void* __restrict__ outp, int M, int N, int K, int rowmap, int act)
{
    __shared__ __align__(16) unsigned short As[128][40];
    __shared__ __align__(16) unsigned short Bs[128][40];

    int tid = threadIdx.x;
    int m0 = blockIdx.x * 128, n0 = blockIdx.y * 128;
    int w = tid >> 6, l = tid & 63;
    int wm = (w >> 1) * 64, wn = (w & 1) * 64;
    int lr = l & 15, lg = l >> 4;

    f32x4 zero = {0.f, 0.f, 0.f, 0.f};
    f32x4 acc[4][4];
    #pragma unroll
    for (int i = 0; i < 4; ++i)
        #pragma unroll
        for (int j = 0; j < 4; ++j) acc[i][j] = zero;

    const float* Af = (const float*)Ap;
    const unsigned short* Ab = (const unsigned short*)Ap;

    for (int k0 = 0; k0 < K; k0 += 32) {
        if (A_BF16) {
            #pragma unroll
            for (int p = 0; p < 2; ++p) {
                int m = p * 64 + (tid >> 2);
                int k8 = (tid & 3) * 8;
                int row = m0 + m;
                u32x4 v = {0u, 0u, 0u, 0u};
                if (row < M) v = *(const u32x4*)(Ab + (size_t)row * K + k0 + k8);
                *(u32x4*)&As[m][k8] = v;
            }
        } else {
            #pragma unroll
            for (int p = 0; p < 4; ++p) {
                int m = p * 32 + (tid >> 3);
                int k4 = (tid & 7) * 4;
                int row = m0 + m;
                float4 v = make_float4(0.f, 0.f, 0.f, 0.f);
                if (row < M) v = ld4(Af + (size_t)row * K + k0 + k4);
                ushort4 c;
                c.x = f2bf(v.x); c.y = f2bf(v.y); c.z = f2bf(v.z); c.w = f2bf(v.w);
                *(ushort4*)&As[m][k4] = c;
            }
        }
        #pragma unroll
        for (int p = 0; p < 2; ++p) {
            int n = p * 64 + (tid >> 2);
            int k8 = (tid & 3) * 8;
            u32x4 v = *(const u32x4*)(WT + (size_t)(n0 + n) * K + k0 + k8);
            *(u32x4*)&Bs[n][k8] = v;
        }
        __syncthreads();

        bf16x8 af[4], bfr[4];
        #pragma unroll
        for (int i = 0; i < 4; ++i)
            af[i] = *(const bf16x8*)&As[wm + i * 16 + lr][lg * 8];
        #pragma unroll
        for (int j = 0; j < 4; ++j)
            bfr[j] = *(const bf16x8*)&Bs[wn + j * 16 + lr][lg * 8];
        #pragma unroll
        for (int i = 0; i < 4; ++i)
            #pragma unroll
            for (int j = 0; j < 4; ++j)
                acc[i][j] = __builtin_amdgcn_mfma_f32_16x16x32_bf16(
                    af[i], bfr[j], acc[i][j], 0, 0, 0);
        __syncthreads();
    }

    // Epilogue. D layout: col = lane&15, row = (lane>>4)*4 + reg [verified].
    #pragma unroll
    for (int i = 0; i < 4; ++i) {
        #pragma unroll
        for (int r = 0; r < 4; ++r) {
            int row = m0 + wm + i * 16 + lg * 4 + r;
            if (row >= M) continue;
            int orow = rowmap ? (row + 1 + row / 3136) : row;
            #pragma unroll
            for (int j = 0; j < 4; ++j) {
                int col = n0 + wn + j * 16 + lr;
                float v = acc[i][j][r] + bias[col];
                if (act) v = 0.5f * v * (1.f + erff(v * 0.70710678118654752f));
                if (resid) v += resid[(size_t)orow * N + col];
                if (OUT_BF16)
                    ((unsigned short*)outp)[(size_t)orow * N + col] = f2bf(v);
                else
                    ((float*)outp)[(size_t)orow * N + col] = v;
            }
        }
    }
}

// ---------------------------------------------------------------------------
// Flash attention fp32: 4 lanes per query (each owns 16 of 64 dims).
// Block = 256 threads = 64 queries. grid: (ceil(Ns/64), 8 heads, NB).
// qkv rows: [q(512)|k(512)|v(512)]. Output (b, n, h*64+d) fp32.
// ---------------------------------------------------------------------------
__global__ __launch_bounds__(256) void attn_kernel(
    const float* __restrict__ qkv, float* __restrict__ o, int Ns)
{
    __shared__ float Ks[32][68];
    __shared__ float Vs[32][68];
    int tid = threadIdx.x;
    int h = blockIdx.y, b = blockIdx.z;
    size_t base = (size_t)b * Ns * 1536;

    int qid = blockIdx.x * 64 + (tid >> 2);
    bool valid = qid < Ns;
    int qr = valid ? qid : Ns - 1;
    int dq = (tid & 3) * 16;

    const float* qp = qkv + base + (size_t)qr * 1536 + h * 64 + dq;
    float4 q[4];
    #pragma unroll
    for (int d = 0; d < 4; ++d) q[d] = f4_scale(ld4(qp + 4 * d), 0.125f);

    float4 oa[4];
    #pragma unroll
    for (int d = 0; d < 4; ++d) oa[d] = make_float4(0.f, 0.f, 0.f, 0.f);
    float mrun = -1e30f, lrun = 0.f;

    int sj = tid >> 3;            // 0..31 : key row
    int skv = (tid >> 2) & 1;     // 0=K, 1=V
    int sc = (tid & 3) * 16;      // 16-float chunk

    int nt = (Ns + 31) / 32;
    for (int kt = 0; kt < nt; ++kt) {
        int krow = kt * 32 + sj;
        int kr = krow < Ns ? krow : Ns - 1;
        const float* sp = qkv + base + (size_t)kr * 1536 + 512 + skv * 512 + h * 64 + sc;
        float* dst = skv ? &Vs[sj][sc] : &Ks[sj][sc];
        #pragma unroll
        for (int d = 0; d < 4; ++d) st4(dst + 4 * d, ld4(sp + 4 * d));
        __syncthreads();

        float s[32];
        #pragma unroll
        for (int j = 0; j < 32; ++j) {
            const float4* kp4 = reinterpret_cast<const float4*>(&Ks[j][dq]);
            float4 a4 = make_float4(0.f, 0.f, 0.f, 0.f);
            #pragma unroll
            for (int d = 0; d < 4; ++d) a4 = f4_fma(q[d], kp4[d], a4);
            float sv = a4.x + a4.y + a4.z + a4.w;
            sv += __shfl_xor(sv, 1);
            sv += __shfl_xor(sv, 2);
            s[j] = (kt * 32 + j < Ns) ? sv : -1e30f;
        }

        float tm = s[0];
        #pragma unroll
        for (int j = 1; j < 32; ++j) tm = fmaxf(tm, s[j]);
        float mnew = fmaxf(mrun, tm);
        float sc_old = __expf(mrun - mnew);
        lrun *= sc_old;
        #pragma unroll
        for (int d = 0; d < 4; ++d) oa[d] = f4_scale(oa[d], sc_old);

        #pragma unroll
        for (int j = 0; j < 32; ++j) {
            float p = __expf(s[j] - mnew);
            lrun += p;
            const float4* vp4 = reinterpret_cast<const float4*>(&Vs[j][dq]);
            #pragma unroll
            for (int d = 0; d < 4; ++d) oa[d] = f4_fmas(p, vp4[d], oa[d]);
        }
        mrun = mnew;
        __syncthreads();
    }

    if (valid) {
        float inv = 1.f / lrun;
        float* op = o + ((size_t)b * Ns + qid) * 512 + h * 64 + dq;
        #pragma unroll
        for (int d = 0; d < 4; ++d) st4(op + 4 * d, f4_scale(oa[d], inv));
    }
}

// ---------------------------------------------------------------------------
extern "C" void kernel_launch(void* const* d_in, const int* in_sizes, int n_in,
                              void* d_out, int out_size, void* d_ws, size_t ws_size,
                              hipStream_t stream)
{
    const float* x       = (const float*)d_in[0];
    const float* ln1_g   = (const float*)d_in[2];
    const float* ln1_b   = (const float*)d_in[3];
    const float* ln2_g   = (const float*)d_in[4];
    const float* ln2_b   = (const float*)d_in[5];
    const float* ln3_g   = (const float*)d_in[6];
    const float* ln3_b   = (const float*)d_in[7];
    const float* g_qkv_w = (const float*)d_in[8];
    const float* g_qkv_b = (const float*)d_in[9];
    const float* g_proj_w= (const float*)d_in[10];
    const float* g_proj_b= (const float*)d_in[11];
    const float* l_qkv_w = (const float*)d_in[12];
    const float* l_qkv_b = (const float*)d_in[13];
    const float* l_proj_w= (const float*)d_in[14];
    const float* l_proj_b= (const float*)d_in[15];
    const float* mlp_w1  = (const float*)d_in[16];
    const float* mlp_b1  = (const float*)d_in[17];
    const float* mlp_w2  = (const float*)d_in[18];
    const float* mlp_b2  = (const float*)d_in[19];

    float* out = (float*)d_out;
    float* buf_a = (float*)d_ws;                            // 6274*512 fp32
    float* buf_b = buf_a + (size_t)6274 * 512;              // 6274*1536 fp32 (or 6274*2048 bf16)
    unsigned short* wbf = (unsigned short*)(buf_b + (size_t)6274 * 1536);
    unsigned short* g_qkv_t = wbf;                          // [1536][512]
    unsigned short* g_proj_t = g_qkv_t + 1536 * 512;        // [512][512]
    unsigned short* l_qkv_t  = g_proj_t + 512 * 512;        // [1536][512]
    unsigned short* l_proj_t = l_qkv_t + 1536 * 512;        // [512][512]
    unsigned short* w1_t     = l_proj_t + 512 * 512;        // [2048][512]
    unsigned short* w2_t     = w1_t + (size_t)2048 * 512;   // [512][2048]

    dim3 tb(32, 8);
    transpose_bf16_kernel<<<dim3(48, 16), tb, 0, stream>>>(g_qkv_w, g_qkv_t, 512, 1536);
    transpose_bf16_kernel<<<dim3(16, 16), tb, 0, stream>>>(g_proj_w, g_proj_t, 512, 512);
    transpose_bf16_kernel<<<dim3(48, 16), tb, 0, stream>>>(l_qkv_w, l_qkv_t, 512, 1536);
    transpose_bf16_kernel<<<dim3(16, 16), tb, 0, stream>>>(l_proj_w, l_proj_t, 512, 512);
    transpose_bf16_kernel<<<dim3(64, 16), tb, 0, stream>>>(mlp_w1, w1_t, 512, 2048);
    transpose_bf16_kernel<<<dim3(16, 64), tb, 0, stream>>>(mlp_w2, w2_t, 2048, 512);

    // 1) ln1 = LN(x)
    ln_kernel<<<6274, 64, 0, stream>>>(x, ln1_g, ln1_b, buf_a, 0);
    // 2) qkv_g
    mfma_gemm<0,0><<<dim3(50, 12), 256, 0, stream>>>(
        buf_a, g_qkv_t, g_qkv_b, nullptr, buf_b, 6274, 1536, 512, 0, 0);
    // 3) global attention
    attn_kernel<<<dim3(50, 8, 2), 256, 0, stream>>>(buf_b, buf_a, 3137);
    // 4) x1 = x + attn @ g_proj
    mfma_gemm<0,0><<<dim3(50, 4), 256, 0, stream>>>(
        buf_a, g_proj_t, g_proj_b, x, out, 6274, 512, 512, 0, 0);
    // 5) ln2 over patch rows
    ln_kernel<<<6272, 64, 0, stream>>>(out, ln2_g, ln2_b, buf_a, 1);
    // 6) qkv_l
    mfma_gemm<0,0><<<dim3(49, 12), 256, 0, stream>>>(
        buf_a, l_qkv_t, l_qkv_b, nullptr, buf_b, 6272, 1536, 512, 0, 0);
    // 7) local attention (32 sub-batches of 196)
    attn_kernel<<<dim3(4, 8, 32), 256, 0, stream>>>(buf_b, buf_a, 196);
    // 8) patches += local @ l_proj  (rowmap)
    mfma_gemm<0,0><<<dim3(49, 4), 256, 0, stream>>>(
        buf_a, l_proj_t, l_proj_b, out, out, 6272, 512, 512, 1, 0);
    // 9) ln3
    ln_kernel<<<6274, 64, 0, stream>>>(out, ln3_g, ln3_b, buf_a, 0);
    // 10) hidden = gelu(ln3 @ w1 + b1) -> bf16
    mfma_gemm<0,1><<<dim3(50, 16), 256, 0, stream>>>(
        buf_a, w1_t, mlp_b1, nullptr, buf_b, 6274, 2048, 512, 0, 1);
    // 11) out = x2 + hidden @ w2 + b2
    mfma_gemm<1,0><<<dim3(50, 4), 256, 0, stream>>>(
        buf_b, w2_t, mlp_b2, out, out, 6274, 512, 2048, 0, 0);
}

// Round 3
// 596.869 us; speedup vs baseline: 7.1173x; 3.6186x over previous
//
#include <hip/hip_runtime.h>
#include <math.h>

typedef __attribute__((ext_vector_type(8))) short bf16x8;
typedef __attribute__((ext_vector_type(4))) float f32x4;
typedef __attribute__((ext_vector_type(4))) unsigned int u32x4;

static __device__ __forceinline__ float4 ld4(const float* p) {
    return *reinterpret_cast<const float4*>(p);
}
static __device__ __forceinline__ void st4(float* p, float4 v) {
    *reinterpret_cast<float4*>(p) = v;
}
static __device__ __forceinline__ unsigned short f2bf(float f) {
    unsigned int u = __float_as_uint(f);
    u += 0x7fffu + ((u >> 16) & 1u);
    return (unsigned short)(u >> 16);
}

// ---------------------------------------------------------------------------
// LayerNorm: one wave per row of 512. mode=1: in_row = r + 1 + r/3136.
// ---------------------------------------------------------------------------
__global__ __launch_bounds__(64) void ln_kernel(
    const float* __restrict__ in, const float* __restrict__ g,
    const float* __restrict__ bta, float* __restrict__ out, int mode)
{
    int r = blockIdx.x;
    int lane = threadIdx.x;
    int in_r = mode ? (r + 1 + r / 3136) : r;
    const float* xp = in + (size_t)in_r * 512 + lane * 8;
    float4 v0 = ld4(xp), v1 = ld4(xp + 4);
    float s  = v0.x + v0.y + v0.z + v0.w + v1.x + v1.y + v1.z + v1.w;
    float sq = v0.x*v0.x + v0.y*v0.y + v0.z*v0.z + v0.w*v0.w
             + v1.x*v1.x + v1.y*v1.y + v1.z*v1.z + v1.w*v1.w;
    #pragma unroll
    for (int off = 32; off; off >>= 1) {
        s  += __shfl_xor(s, off);
        sq += __shfl_xor(sq, off);
    }
    float mean = s * (1.f / 512.f);
    float var  = fmaxf(sq * (1.f / 512.f) - mean * mean, 0.f);
    float rstd = rsqrtf(var + 1e-5f);
    float4 g0 = ld4(g + lane * 8),   g1 = ld4(g + lane * 8 + 4);
    float4 b0 = ld4(bta + lane * 8), b1 = ld4(bta + lane * 8 + 4);
    float4 r0, r1;
    r0.x = (v0.x - mean) * rstd * g0.x + b0.x;
    r0.y = (v0.y - mean) * rstd * g0.y + b0.y;
    r0.z = (v0.z - mean) * rstd * g0.z + b0.z;
    r0.w = (v0.w - mean) * rstd * g0.w + b0.w;
    r1.x = (v1.x - mean) * rstd * g1.x + b1.x;
    r1.y = (v1.y - mean) * rstd * g1.y + b1.y;
    r1.z = (v1.z - mean) * rstd * g1.z + b1.z;
    r1.w = (v1.w - mean) * rstd * g1.w + b1.w;
    float* op = out + (size_t)r * 512 + lane * 8;
    st4(op, r0);
    st4(op + 4, r1);
}

// ---------------------------------------------------------------------------
// Weight transpose + fp32->bf16: W[K][N] -> WT[N][K] bf16.
// ---------------------------------------------------------------------------
__global__ __launch_bounds__(256) void transpose_bf16_kernel(
    const float* __restrict__ W, unsigned short* __restrict__ WT, int K, int N)
{
    __shared__ unsigned short tile[32][34];
    int tx = threadIdx.x, ty = threadIdx.y;
    int bx = blockIdx.x * 32, by = blockIdx.y * 32;
    #pragma unroll
    for (int r = 0; r < 32; r += 8)
        tile[ty + r][tx] = f2bf(W[(size_t)(by + ty + r) * N + bx + tx]);
    __syncthreads();
    #pragma unroll
    for (int r = 0; r < 32; r += 8)
        WT[(size_t)(bx + ty + r) * K + by + tx] = tile[tx][ty + r];
}

// ---------------------------------------------------------------------------
// MFMA bf16 GEMM: out[maprow(m)] (+)= A[m,:] @ WT[n,:] + bias[n] (+gelu)(+resid)
// ---------------------------------------------------------------------------
template<int A_BF16, int OUT_BF16>
__global__ __launch_bounds__(256) void mfma_gemm(
    const void* __restrict__ Ap, const unsigned short* __restrict__ WT,
    const float* __restrict__ bias, const float* __restrict__ resid,
    void* __restrict__ outp, int M, int N, int K, int rowmap, int act)
{
    __shared__ __align__(16) unsigned short As[128][40];
    __shared__ __align__(16) unsigned short Bs[128][40];

    int tid = threadIdx.x;
    int m0 = blockIdx.x * 128, n0 = blockIdx.y * 128;
    int w = tid >> 6, l = tid & 63;
    int wm = (w >> 1) * 64, wn = (w & 1) * 64;
    int lr = l & 15, lg = l >> 4;

    f32x4 zero = {0.f, 0.f, 0.f, 0.f};
    f32x4 acc[4][4];
    #pragma unroll
    for (int i = 0; i < 4; ++i)
        #pragma unroll
        for (int j = 0; j < 4; ++j) acc[i][j] = zero;

    const float* Af = (const float*)Ap;
    const unsigned short* Ab = (const unsigned short*)Ap;

    for (int k0 = 0; k0 < K; k0 += 32) {
        if (A_BF16) {
            #pragma unroll
            for (int p = 0; p < 2; ++p) {
                int m = p * 64 + (tid >> 2);
                int k8 = (tid & 3) * 8;
                int row = m0 + m;
                u32x4 v = {0u, 0u, 0u, 0u};
                if (row < M) v = *(const u32x4*)(Ab + (size_t)row * K + k0 + k8);
                *(u32x4*)&As[m][k8] = v;
            }
        } else {
            #pragma unroll
            for (int p = 0; p < 4; ++p) {
                int m = p * 32 + (tid >> 3);
                int k4 = (tid & 7) * 4;
                int row = m0 + m;
                float4 v = make_float4(0.f, 0.f, 0.f, 0.f);
                if (row < M) v = ld4(Af + (size_t)row * K + k0 + k4);
                ushort4 c;
                c.x = f2bf(v.x); c.y = f2bf(v.y); c.z = f2bf(v.z); c.w = f2bf(v.w);
                *(ushort4*)&As[m][k4] = c;
            }
        }
        #pragma unroll
        for (int p = 0; p < 2; ++p) {
            int n = p * 64 + (tid >> 2);
            int k8 = (tid & 3) * 8;
            u32x4 v = *(const u32x4*)(WT + (size_t)(n0 + n) * K + k0 + k8);
            *(u32x4*)&Bs[n][k8] = v;
        }
        __syncthreads();

        bf16x8 af[4], bfr[4];
        #pragma unroll
        for (int i = 0; i < 4; ++i)
            af[i] = *(const bf16x8*)&As[wm + i * 16 + lr][lg * 8];
        #pragma unroll
        for (int j = 0; j < 4; ++j)
            bfr[j] = *(const bf16x8*)&Bs[wn + j * 16 + lr][lg * 8];
        #pragma unroll
        for (int i = 0; i < 4; ++i)
            #pragma unroll
            for (int j = 0; j < 4; ++j)
                acc[i][j] = __builtin_amdgcn_mfma_f32_16x16x32_bf16(
                    af[i], bfr[j], acc[i][j], 0, 0, 0);
        __syncthreads();
    }

    #pragma unroll
    for (int i = 0; i < 4; ++i) {
        #pragma unroll
        for (int r = 0; r < 4; ++r) {
            int row = m0 + wm + i * 16 + lg * 4 + r;
            if (row >= M) continue;
            int orow = rowmap ? (row + 1 + row / 3136) : row;
            #pragma unroll
            for (int j = 0; j < 4; ++j) {
                int col = n0 + wn + j * 16 + lr;
                float v = acc[i][j][r] + bias[col];
                if (act) v = 0.5f * v * (1.f + erff(v * 0.70710678118654752f));
                if (resid) v += resid[(size_t)orow * N + col];
                if (OUT_BF16)
                    ((unsigned short*)outp)[(size_t)orow * N + col] = f2bf(v);
                else
                    ((float*)outp)[(size_t)orow * N + col] = v;
            }
        }
    }
}

// ---------------------------------------------------------------------------
// MFMA flash attention, bf16. One block = one (batch,head) x 64 q-rows.
// qkv bf16 rows [q(512)|k(512)|v(512)], row = b*Ns + n. Out bf16 [b*Ns+n][512].
// S^T = mfma(K_frag, Q_frag): lane holds q=lane&15, keys=(lane>>4)*4+reg(+16f).
// O^T = mfma(V^T_frag, P^T_frag): accumulate d=(16j+4g+r), q=lane&15.
// Ks/Vs: [32][64] ushort, 16B-chunk swizzle: schunk = chunk ^ (k&7) ^ (k>>3).
// ---------------------------------------------------------------------------
__global__ __launch_bounds__(256) void attn_mfma(
    const unsigned short* __restrict__ qkv, unsigned short* __restrict__ o, int Ns)
{
    __shared__ __align__(16) unsigned short Ks[32 * 64];
    __shared__ __align__(16) unsigned short Vs[32 * 64];
    __shared__ __align__(16) unsigned short PTs[4][32 * 20];

    int tid = threadIdx.x;
    int h = blockIdx.y, b = blockIdx.z;
    size_t base = (size_t)b * Ns * 1536;
    int w = tid >> 6, l = tid & 63;
    int g = l >> 4, c16 = l & 15;

    // Q fragments (B-operand of S^T): wave w owns q rows qt*64 + w*16 + c16.
    int q0 = blockIdx.x * 64 + w * 16;
    int qrow = q0 + c16;
    int qr = qrow < Ns ? qrow : Ns - 1;
    const unsigned short* qp = qkv + base + (size_t)qr * 1536 + h * 64;
    bf16x8 bQ0 = *(const bf16x8*)(qp + g * 8);
    bf16x8 bQ1 = *(const bf16x8*)(qp + 32 + g * 8);

    f32x4 zero = {0.f, 0.f, 0.f, 0.f};
    f32x4 Oacc[4];
    #pragma unroll
    for (int j = 0; j < 4; ++j) Oacc[j] = zero;
    float mrun = -1e30f, lrun = 0.f;

    // staging: thread t loads key-row sk, 16B chunk sch (swizzled dest).
    int sk = tid >> 3;
    int sch = tid & 7;
    int kdst = sk * 64 + ((sch ^ (sk & 7) ^ (sk >> 3)) * 8);

    int nt = (Ns + 31) / 32;
    for (int kt = 0; kt < nt; ++kt) {
        int kr = kt * 32 + sk;
        if (kr >= Ns) kr = Ns - 1;
        const unsigned short* kp = qkv + base + (size_t)kr * 1536 + 512 + h * 64 + sch * 8;
        u32x4 kv = *(const u32x4*)kp;
        u32x4 vv = *(const u32x4*)(kp + 512);
        __syncthreads();                    // prev tile fully consumed
        *(u32x4*)&Ks[kdst] = kv;
        *(u32x4*)&Vs[kdst] = vv;
        __syncthreads();                    // staging visible

        // ---- S^T = K . Q^T  (2 key-frags x 2 k-chunks) ----
        f32x4 st0 = zero, st1 = zero;
        #pragma unroll
        for (int f = 0; f < 2; ++f) {
            int key = 16 * f + c16;
            int swz = (key & 7) ^ (key >> 3);
            bf16x8 aK0 = *(const bf16x8*)&Ks[key * 64 + ((g ^ swz) * 8)];
            bf16x8 aK1 = *(const bf16x8*)&Ks[key * 64 + (((4 + g) ^ swz) * 8)];
            f32x4 acc = (f == 0) ? st0 : st1;
            acc = __builtin_amdgcn_mfma_f32_16x16x32_bf16(aK0, bQ0, acc, 0, 0, 0);
            acc = __builtin_amdgcn_mfma_f32_16x16x32_bf16(aK1, bQ1, acc, 0, 0, 0);
            if (f == 0) st0 = acc; else st1 = acc;
        }

        // ---- online softmax (per-lane: one q = c16, 8 key values) ----
        float sv[8];
        float mloc = -1e30f;
        #pragma unroll
        for (int f = 0; f < 2; ++f) {
            #pragma unroll
            for (int r = 0; r < 4; ++r) {
                int kg = kt * 32 + 16 * f + 4 * g + r;
                float s = ((f == 0) ? st0[r] : st1[r]) * 0.125f;
                s = (kg < Ns) ? s : -1e30f;
                sv[f * 4 + r] = s;
                mloc = fmaxf(mloc, s);
            }
        }
        mloc = fmaxf(mloc, __shfl_xor(mloc, 16));
        mloc = fmaxf(mloc, __shfl_xor(mloc, 32));
        float mnew = fmaxf(mrun, mloc);
        float scale = __expf(mrun - mnew);
        float p[8];
        float psum = 0.f;
        #pragma unroll
        for (int e = 0; e < 8; ++e) { p[e] = __expf(sv[e] - mnew); psum += p[e]; }
        psum += __shfl_xor(psum, 16);
        psum += __shfl_xor(psum, 32);
        lrun = lrun * scale + psum;
        mrun = mnew;
        #pragma unroll
        for (int j = 0; j < 4; ++j) {
            Oacc[j][0] *= scale; Oacc[j][1] *= scale;
            Oacc[j][2] *= scale; Oacc[j][3] *= scale;
        }

        // ---- P^T to per-wave LDS: PTs[key][q], stride 20 ----
        unsigned short* pt = PTs[w];
        #pragma unroll
        for (int f = 0; f < 2; ++f)
            #pragma unroll
            for (int r = 0; r < 4; ++r)
                pt[(16 * f + 4 * g + r) * 20 + c16] = f2bf(p[f * 4 + r]);
        asm volatile("s_waitcnt lgkmcnt(0)" ::: "memory");
        __builtin_amdgcn_sched_barrier(0);

        bf16x8 bPT;
        #pragma unroll
        for (int i = 0; i < 8; ++i)
            bPT[i] = (short)pt[(g * 8 + i) * 20 + c16];

        // ---- O^T += V^T . P^T ----
        #pragma unroll
        for (int j = 0; j < 4; ++j) {
            int vch = 2 * j + (c16 >> 3);
            bf16x8 aV;
            #pragma unroll
            for (int i = 0; i < 8; ++i)
                aV[i] = (short)Vs[(g * 8 + i) * 64 + ((vch ^ i ^ g) * 8) + (c16 & 7)];
            Oacc[j] = __builtin_amdgcn_mfma_f32_16x16x32_bf16(aV, bPT, Oacc[j], 0, 0, 0);
        }
    }

    if (qrow < Ns) {
        float linv = 1.f / lrun;
        unsigned short* op = o + ((size_t)b * Ns + qrow) * 512 + h * 64;
        #pragma unroll
        for (int j = 0; j < 4; ++j)
            #pragma unroll
            for (int r = 0; r < 4; ++r)
                op[16 * j + 4 * g + r] = f2bf(Oacc[j][r] * linv);
    }
}

// ---------------------------------------------------------------------------
extern "C" void kernel_launch(void* const* d_in, const int* in_sizes, int n_in,
                              void* d_out, int out_size, void* d_ws, size_t ws_size,
                              hipStream_t stream)
{
    const float* x       = (const float*)d_in[0];
    const float* ln1_g   = (const float*)d_in[2];
    const float* ln1_b   = (const float*)d_in[3];
    const float* ln2_g   = (const float*)d_in[4];
    const float* ln2_b   = (const float*)d_in[5];
    const float* ln3_g   = (const float*)d_in[6];
    const float* ln3_b   = (const float*)d_in[7];
    const float* g_qkv_w = (const float*)d_in[8];
    const float* g_qkv_b = (const float*)d_in[9];
    const float* g_proj_w= (const float*)d_in[10];
    const float* g_proj_b= (const float*)d_in[11];
    const float* l_qkv_w = (const float*)d_in[12];
    const float* l_qkv_b = (const float*)d_in[13];
    const float* l_proj_w= (const float*)d_in[14];
    const float* l_proj_b= (const float*)d_in[15];
    const float* mlp_w1  = (const float*)d_in[16];
    const float* mlp_b1  = (const float*)d_in[17];
    const float* mlp_w2  = (const float*)d_in[18];
    const float* mlp_b2  = (const float*)d_in[19];

    float* out = (float*)d_out;
    float* buf_a = (float*)d_ws;                            // 6274*512 fp32 / bf16
    float* buf_b = buf_a + (size_t)6274 * 512;              // qkv bf16 / hidden bf16
    unsigned short* wbf = (unsigned short*)(buf_b + (size_t)6274 * 1536);
    unsigned short* g_qkv_t = wbf;
    unsigned short* g_proj_t = g_qkv_t + 1536 * 512;
    unsigned short* l_qkv_t  = g_proj_t + 512 * 512;
    unsigned short* l_proj_t = l_qkv_t + 1536 * 512;
    unsigned short* w1_t     = l_proj_t + 512 * 512;
    unsigned short* w2_t     = w1_t + (size_t)2048 * 512;

    unsigned short* qkv_bf  = (unsigned short*)buf_b;
    unsigned short* attn_bf = (unsigned short*)buf_a;

    dim3 tb(32, 8);
    transpose_bf16_kernel<<<dim3(48, 16), tb, 0, stream>>>(g_qkv_w, g_qkv_t, 512, 1536);
    transpose_bf16_kernel<<<dim3(16, 16), tb, 0, stream>>>(g_proj_w, g_proj_t, 512, 512);
    transpose_bf16_kernel<<<dim3(48, 16), tb, 0, stream>>>(l_qkv_w, l_qkv_t, 512, 1536);
    transpose_bf16_kernel<<<dim3(16, 16), tb, 0, stream>>>(l_proj_w, l_proj_t, 512, 512);
    transpose_bf16_kernel<<<dim3(64, 16), tb, 0, stream>>>(mlp_w1, w1_t, 512, 2048);
    transpose_bf16_kernel<<<dim3(16, 64), tb, 0, stream>>>(mlp_w2, w2_t, 2048, 512);

    // 1) ln1 = LN(x)
    ln_kernel<<<6274, 64, 0, stream>>>(x, ln1_g, ln1_b, buf_a, 0);
    // 2) qkv_g -> bf16
    mfma_gemm<0,1><<<dim3(50, 12), 256, 0, stream>>>(
        buf_a, g_qkv_t, g_qkv_b, nullptr, qkv_bf, 6274, 1536, 512, 0, 0);
    // 3) global attention (bf16 in/out)
    attn_mfma<<<dim3(50, 8, 2), 256, 0, stream>>>(qkv_bf, attn_bf, 3137);
    // 4) x1 = x + attn @ g_proj
    mfma_gemm<1,0><<<dim3(50, 4), 256, 0, stream>>>(
        attn_bf, g_proj_t, g_proj_b, x, out, 6274, 512, 512, 0, 0);
    // 5) ln2 over patch rows
    ln_kernel<<<6272, 64, 0, stream>>>(out, ln2_g, ln2_b, buf_a, 1);
    // 6) qkv_l -> bf16
    mfma_gemm<0,1><<<dim3(49, 12), 256, 0, stream>>>(
        buf_a, l_qkv_t, l_qkv_b, nullptr, qkv_bf, 6272, 1536, 512, 0, 0);
    // 7) local attention (32 sub-batches of 196)
    attn_mfma<<<dim3(4, 8, 32), 256, 0, stream>>>(qkv_bf, attn_bf, 196);
    // 8) patches += local @ l_proj  (rowmap)
    mfma_gemm<1,0><<<dim3(49, 4), 256, 0, stream>>>(
        attn_bf, l_proj_t, l_proj_b, out, out, 6272, 512, 512, 1, 0);
    // 9) ln3
    ln_kernel<<<6274, 64, 0, stream>>>(out, ln3_g, ln3_b, buf_a, 0);
    // 10) hidden = gelu(ln3 @ w1 + b1) -> bf16
    mfma_gemm<0,1><<<dim3(50, 16), 256, 0, stream>>>(
        buf_a, w1_t, mlp_b1, nullptr, buf_b, 6274, 2048, 512, 0, 1);
    // 11) out = x2 + hidden @ w2 + b2
    mfma_gemm<1,0><<<dim3(50, 4), 256, 0, stream>>>(
        buf_b, w2_t, mlp_b2, out, out, 6274, 512, 2048, 0, 0);
}